// Round 6
// baseline (336.786 us; speedup 1.0000x reference)
//
#include <hip/hip_runtime.h>

// Point transformer B=1 N=512 D=256 H=8 HD=32 CD=3 HID=682.
// hidden[i,j,e] = silu(aI[e]-p[j,e]); e^{-(aI-p)} = e^{-aI} * e^{p}.
// rel_value contracted: G[i,h,e]=sum_j w*silu_v -> ctx2 = G@rv2^T + rv2_b (exact).
// rb2_b cancels in softmax.
// Key restructure vs prior rounds: register-block over Mi query rows so every
// table fragment load feeds Mi MFMAs; scores/weights live in ONE buffer (WB)
// stored in MFMA B-fragment order (f16 raw scores -> in-place softmax -> bf16 w),
// consumed by both the G-GEMM (B-operand) and ctx1-GEMM (B-operand).
// ctx GEMMs computed transposed (out[c,i]) so A-operands (vT, rv2) are frags.
// FFN kernels Mi=16-blocked to stop re-reading weights per i-pair.

#define NN 512
#define DD 256
#define HH 8
#define HIDN 682
#define QKSCALE 0.17677669529663687f

// ---- workspace (floats); max end = 1,507,392 = 5.90 MB ----
#define OFF_QB    0        // [65536]  q*scale bf16 rows [i][128dw]   (k2->k3a)
#define OFF_PB    65536    // [65536]  p_b f16 frags [jt][ks][lane]u4 (k1->k3a)
#define OFF_X2    0        // [131072] x+attn (k3c->k5)  overlays QB/PB
#define OFF_KF    131072   // [65536]  k bf16 A-frags (k2->k3a)
#define OFF_RB2F  196608   // [2048]   rb2 B-frags (k1->k3a)
#define OFF_XN2   131072   // [131072] LN2 out (k3c->k4) overlays KF/RB2F
#define OFF_RV2F  262144   // [32768]  rv2 bf16 A-frags [mt][ks2][lane]u4 (k1->k3c)
#define OFF_VT    294912   // [65536]  v^T bf16 [c][256dw] (k2->k3c)
#define OFF_PV    360448   // [65536]  p_v f16 frags [et][ks][lane]u4 (k1->k3c)
#define OFF_WB    425984   // [1081408] scores/weights [528i][16ks][32slot][4dw]+64
#define OFF_XN    425984   // [131072] LN1 out (k1->k2, inside WB region)
#define OFF_QKVP  557056   // [196608] qkv_w k-major f4 (k1->k2, inside WB region)
#define OFF_W12P  425984   // [349184] ffn w1/w2 k-major (k3p->k4, WB dead)
#define OFF_W3P   775168   // [174592] ffn w3 k-major (k3p->k5)
#define OFF_H1    949760   // [349184] swiglu hidden (k4->k5)

typedef float  f32x4  __attribute__((ext_vector_type(4)));
typedef short  bf16x8 __attribute__((ext_vector_type(8)));
typedef __fp16 fp16x2 __attribute__((ext_vector_type(2)));
typedef unsigned int u32;

static __device__ __forceinline__ float wredSum(float v){
#pragma unroll
  for (int o = 1; o < 64; o <<= 1) v += __shfl_xor(v, o, 64);
  return v;
}
static __device__ __forceinline__ float wredMax(float v){
#pragma unroll
  for (int o = 1; o < 64; o <<= 1) v = fmaxf(v, __shfl_xor(v, o, 64));
  return v;
}
static __device__ __forceinline__ float fsilu(float x){
  return x * __builtin_amdgcn_rcpf(1.0f + __expf(-x));
}
static __device__ __forceinline__ u32 cvtpk(float lo, float hi){  // 2xf32 -> bf16 pair
  u32 d; asm("v_cvt_pk_bf16_f32 %0, %1, %2" : "=v"(d) : "v"(lo), "v"(hi));
  return d;
}
static __device__ __forceinline__ u32 pkf16(float lo, float hi){  // 2xf32 -> f16 pair
  fp16x2 r = __builtin_amdgcn_cvt_pkrtz(lo, hi);
  union{fp16x2 h; u32 u;} c; c.h = r; return c.u;
}
static __device__ __forceinline__ float f16lo(u32 d){
  union{unsigned short s; __fp16 h;} c; c.s = (unsigned short)(d & 0xffffu); return (float)c.h;
}
static __device__ __forceinline__ float f16hi(u32 d){
  union{unsigned short s; __fp16 h;} c; c.s = (unsigned short)(d >> 16); return (float)c.h;
}
static __device__ __forceinline__ bf16x8 mkfrag(u32 a, u32 b, u32 c, u32 d){
  union{u32 u[4]; bf16x8 s;} f; f.u[0]=a; f.u[1]=b; f.u[2]=c; f.u[3]=d; return f.s;
}
static __device__ __forceinline__ float dot4(float4 a, float4 b){
  return a.x*b.x + a.y*b.y + a.z*b.z + a.w*b.w;
}

// ---------- K1: LN1 + table builders (601 blocks) ----------
__global__ __launch_bounds__(256) void k1_prep(
    const float* __restrict__ x, const float* __restrict__ coords,
    const float* __restrict__ ln1_w, const float* __restrict__ ln1_b,
    const float* __restrict__ rb1_w, const float* __restrict__ rv1_w,
    const float* __restrict__ rv2_w, const float* __restrict__ rb2_w,
    const float* __restrict__ qkv_w, float* __restrict__ ws)
{
  __shared__ float r4[4];
  const int b = blockIdx.x, t = threadIdx.x;
  if (b < 512) {                         // ---- LN1 ----
    const int lane = t & 63, wid = t >> 6;
    const float v = x[b*DD + t];
    float s = wredSum(v);
    if (lane == 0) r4[wid] = s;
    __syncthreads();
    const float mu = (r4[0]+r4[1]+r4[2]+r4[3]) * (1.0f/DD);
    const float d = v - mu;
    float s2 = wredSum(d*d);
    __syncthreads();
    if (lane == 0) r4[wid] = s2;
    __syncthreads();
    const float var = (r4[0]+r4[1]+r4[2]+r4[3]) * (1.0f/DD);
    ws[OFF_XN + b*DD + t] = d*rsqrtf(var + 1e-5f)*ln1_w[t] + ln1_b[t];
  } else if (b < 528) {                  // ---- PB f16 frags ----
    u32* PB32 = (u32*)(ws + OFF_PB);
#pragma unroll
    for (int k = 0; k < 4; ++k) {
      const int L = (b-512)*1024 + k*256 + t;           // uint4 index
      const int jt = L >> 9, ks = (L >> 6) & 7, ln = L & 63;
      const int lmm = ln & 15, lgg = ln >> 4;
      const int j = jt*16 + lmm, e0 = ks*32 + lgg*8;
      const float c0 = coords[j*3], c1 = coords[j*3+1], c2 = coords[j*3+2];
      float p[8];
#pragma unroll
      for (int r = 0; r < 8; ++r)
        p[r] = c0*rb1_w[(e0+r)*3] + c1*rb1_w[(e0+r)*3+1] + c2*rb1_w[(e0+r)*3+2];
      uint4 q; q.x = pkf16(p[0],p[1]); q.y = pkf16(p[2],p[3]);
      q.z = pkf16(p[4],p[5]); q.w = pkf16(p[6],p[7]);
      *(uint4*)(PB32 + (size_t)L*4) = q;
    }
  } else if (b < 544) {                  // ---- PV f16 frags ----
    u32* PV32 = (u32*)(ws + OFF_PV);
#pragma unroll
    for (int k = 0; k < 4; ++k) {
      const int L = (b-528)*1024 + k*256 + t;
      const int et = L >> 10, ks = (L >> 6) & 15, ln = L & 63;
      const int lmm = ln & 15, lgg = ln >> 4;
      const int e = et*16 + lmm, j0 = ks*32 + lgg*8;
      const float w0 = rv1_w[e*3], w1 = rv1_w[e*3+1], w2 = rv1_w[e*3+2];
      float p[8];
#pragma unroll
      for (int r = 0; r < 8; ++r)
        p[r] = coords[(j0+r)*3]*w0 + coords[(j0+r)*3+1]*w1 + coords[(j0+r)*3+2]*w2;
      uint4 q; q.x = pkf16(p[0],p[1]); q.y = pkf16(p[2],p[3]);
      q.z = pkf16(p[4],p[5]); q.w = pkf16(p[6],p[7]);
      *(uint4*)(PV32 + (size_t)L*4) = q;
    }
  } else if (b < 552) {                  // ---- RV2F bf16 A-frags ----
    u32* RV32 = (u32*)(ws + OFF_RV2F);
#pragma unroll
    for (int k = 0; k < 4; ++k) {
      const int L = (b-544)*1024 + k*256 + t;
      const int mt = L >> 9, ks2 = (L >> 6) & 7, ln = L & 63;
      const int lmm = ln & 15, lgg = ln >> 4;
      const int c = mt*16 + lmm, e0 = ks2*32 + lgg*8;
      const float4 f0 = *(const float4*)(rv2_w + c*DD + e0);
      const float4 f1 = *(const float4*)(rv2_w + c*DD + e0 + 4);
      uint4 q; q.x = cvtpk(f0.x,f0.y); q.y = cvtpk(f0.z,f0.w);
      q.z = cvtpk(f1.x,f1.y); q.w = cvtpk(f1.z,f1.w);
      *(uint4*)(RV32 + (size_t)L*4) = q;
    }
  } else if (b == 552) {                 // ---- RB2F B-frags ----
    u32* RBF = (u32*)(ws + OFF_RB2F);
    const int l = t & 63, lmm = l & 15, lgg = (l >> 4) & 3, kq = t >> 6;
#pragma unroll
    for (int g = 0; g < 2; ++g) {
      const int ks = g*4 + kq;
      u32 dw[4];
#pragma unroll
      for (int dd = 0; dd < 4; ++dd) {
        const int e0 = ks*32 + lgg*8 + 2*dd;
        const float f0 = (lmm < HH) ? rb2_w[lmm*DD + e0]     : 0.f;
        const float f1 = (lmm < HH) ? rb2_w[lmm*DD + e0 + 1] : 0.f;
        dw[dd] = cvtpk(f0, f1);
      }
      uint4 q4; q4.x = dw[0]; q4.y = dw[1]; q4.z = dw[2]; q4.w = dw[3];
      *(uint4*)(RBF + (ks*64 + l)*4) = q4;
    }
  } else {                               // ---- QKVP f4[k4][768] ----
    float4* dst = (float4*)(ws + OFF_QKVP);
#pragma unroll
    for (int k = 0; k < 4; ++k) {
      const int L4 = (b - 553)*1024 + k*256 + t;
      const int O = L4 % 768, k4 = L4 / 768;
      dst[L4] = *(const float4*)(qkv_w + O*DD + k4*4);
    }
  }
}

// ---------- K2: QKV GEMM -> QB (q*scale bf16), KF (k frags), VT (v^T bf16) ----------
__global__ __launch_bounds__(256) void k2_qkv(
    float* __restrict__ ws, const float* __restrict__ qkv_b)
{
  const int i0 = blockIdx.x*2, rep = blockIdx.y, t = threadIdx.x;
  const int O = rep*DD + t;
  const float4* xn4 = (const float4*)(ws + OFF_XN);
  const float4* wp4 = (const float4*)(ws + OFF_QKVP);
  float a0 = qkv_b[O], a1 = a0;
  for (int k4 = 0; k4 < 64; ++k4) {
    const float4 w = wp4[k4*768 + O];
    const float4 x0 = xn4[i0*64 + k4];        // uniform -> s_load
    const float4 x1 = xn4[i0*64 + 64 + k4];
    a0 += dot4(x0, w);
    a1 += dot4(x1, w);
  }
  if (rep == 0) {                             // q*scale -> bf16 rows [i][128dw]
    u32* QB = (u32*)(ws + OFF_QB);
    const float s0 = a0*QKSCALE, s1 = a1*QKSCALE;
    const float p0 = __shfl_xor(s0, 1);
    const float p1 = __shfl_xor(s1, 1);
    if ((t & 1) == 0) {
      QB[i0*128 + (t >> 1)]     = cvtpk(s0, p0);
      QB[(i0+1)*128 + (t >> 1)] = cvtpk(s1, p1);
    }
  } else if (rep == 1) {                      // k -> bf16 A-fragment layout
    u32* KF = (u32*)(ws + OFF_KF);
    const float p0 = __shfl_xor(a0, 1);
    const float p1 = __shfl_xor(a1, 1);
    if ((t & 1) == 0) {
      const int hq = t >> 5, lgk = (t >> 3) & 3, dw = (t & 7) >> 1;
      const int jt0_ = i0 >> 4, lm0 = i0 & 15;
      KF[(((jt0_*8 + hq)*4 + lgk)*16 + lm0)*4 + dw] = cvtpk(a0, p0);
      const int j1 = i0 + 1, jt1_ = j1 >> 4, lm1 = j1 & 15;
      KF[(((jt1_*8 + hq)*4 + lgk)*16 + lm1)*4 + dw] = cvtpk(a1, p1);
    }
  } else {                                    // v^T bf16 [c][256dw], dword = j-pair
    u32* VT = (u32*)(ws + OFF_VT);
    VT[t*256 + (i0 >> 1)] = cvtpk(a0, a1);
  }
}

// ---------- K3a: scores (bias-GEMM + qk) -> WB raw f16, Mi=4 x j-quarter ----------
__global__ __launch_bounds__(256, 2) void k3a_scores(
    const float* __restrict__ coords, const float* __restrict__ rb1_w,
    const float* __restrict__ rb1_b, float* __restrict__ ws)
{
  __shared__ __align__(16) float aI4[4][DD];
  __shared__ __align__(16) float eI4[4][DD];
  const int bx = blockIdx.x, t = threadIdx.x;
  const int it = bx >> 2, jq = bx & 3, i0 = it*4;
  const int lane = t & 63, w = t >> 6, lm = lane & 15, lg = lane >> 4;
  {
    const float w0 = rb1_w[t*3], w1 = rb1_w[t*3+1], w2 = rb1_w[t*3+2], bb = rb1_b[t];
#pragma unroll
    for (int i = 0; i < 4; ++i) {
      const float a = coords[(i0+i)*3]*w0 + coords[(i0+i)*3+1]*w1
                    + coords[(i0+i)*3+2]*w2 + bb;
      aI4[i][t] = a; eI4[i][t] = __expf(-a);
    }
  }
  __syncthreads();
  const uint4* PBu = (const uint4*)(ws + OFF_PB);
  const uint4* KFu = (const uint4*)(ws + OFF_KF);
  const uint4* QBu = (const uint4*)(ws + OFF_QB);
  const u32*   RBF = (const u32*)(ws + OFF_RB2F);
  const int jtA = jq*8 + w*2;
  f32x4 z = {0,0,0,0};
  f32x4 acc[2][4] = {{z,z,z,z},{z,z,z,z}};
  for (int ks = 0; ks < 8; ++ks) {
    const uint4 bd = *(const uint4*)(RBF + (ks*64 + lane)*4);
    const bf16x8 bfr = mkfrag(bd.x,bd.y,bd.z,bd.w);
    float4 aA[4][2], eA[4][2];
#pragma unroll
    for (int i = 0; i < 4; ++i) {
      aA[i][0] = *(const float4*)&aI4[i][ks*32 + lg*8];
      aA[i][1] = *(const float4*)&aI4[i][ks*32 + lg*8 + 4];
      eA[i][0] = *(const float4*)&eI4[i][ks*32 + lg*8];
      eA[i][1] = *(const float4*)&eI4[i][ks*32 + lg*8 + 4];
    }
#pragma unroll
    for (int j2 = 0; j2 < 2; ++j2) {
      const uint4 pd = PBu[((jtA+j2)*8 + ks)*64 + lane];
      float p[8], ep[8];
      p[0]=f16lo(pd.x); p[1]=f16hi(pd.x); p[2]=f16lo(pd.y); p[3]=f16hi(pd.y);
      p[4]=f16lo(pd.z); p[5]=f16hi(pd.z); p[6]=f16lo(pd.w); p[7]=f16hi(pd.w);
#pragma unroll
      for (int r = 0; r < 8; ++r) ep[r] = __expf(p[r]);
#pragma unroll
      for (int i = 0; i < 4; ++i) {
        const float* aa = (const float*)&aA[i][0];
        const float* ee = (const float*)&eA[i][0];
        float s[8];
#pragma unroll
        for (int r = 0; r < 8; ++r)
          s[r] = (aa[r] - p[r]) * __builtin_amdgcn_rcpf(fmaf(ee[r], ep[r], 1.f));
        const bf16x8 afr = mkfrag(cvtpk(s[0],s[1]), cvtpk(s[2],s[3]),
                                  cvtpk(s[4],s[5]), cvtpk(s[6],s[7]));
        acc[j2][i] = __builtin_amdgcn_mfma_f32_16x16x32_bf16(afr, bfr, acc[j2][i], 0,0,0);
      }
    }
  }
#pragma unroll
  for (int hq = 0; hq < 8; ++hq) {
    uint4 qd[4];
#pragma unroll
    for (int i = 0; i < 4; ++i) qd[i] = QBu[(i0+i)*32 + hq*4 + lg];
    const bool sel = (lm == hq);
#pragma unroll
    for (int j2 = 0; j2 < 2; ++j2) {
      const uint4 kd = KFu[((jtA+j2)*8 + hq)*64 + lane];
      const bf16x8 kfr = mkfrag(kd.x,kd.y,kd.z,kd.w);
#pragma unroll
      for (int i = 0; i < 4; ++i) {
        const bf16x8 qfr = mkfrag(sel?qd[i].x:0u, sel?qd[i].y:0u,
                                  sel?qd[i].z:0u, sel?qd[i].w:0u);
        acc[j2][i] = __builtin_amdgcn_mfma_f32_16x16x32_bf16(kfr, qfr, acc[j2][i], 0,0,0);
      }
    }
  }
  // store raw f16 scores into WB fragment layout
  u32* WB = (u32*)(ws + OFF_WB);
  if (lm < HH) {
#pragma unroll
    for (int j2 = 0; j2 < 2; ++j2) {
      const int jt = jtA + j2, j0 = jt*16 + lg*4;
      const int ksw = j0 >> 5, rr = j0 & 31, lgw = rr >> 3, d0 = (rr & 7) >> 1;
#pragma unroll
      for (int i = 0; i < 4; ++i) {
        const int idx = (((i0+i)*16 + ksw)*32 + lgw*8 + lm)*4 + d0;
        uint2 st; st.x = pkf16(acc[j2][i][0], acc[j2][i][1]);
        st.y = pkf16(acc[j2][i][2], acc[j2][i][3]);
        *(uint2*)(WB + idx) = st;
      }
    }
  }
}

// ---------- K3b: softmax in-place on WB (f16 scores -> bf16 weights) ----------
__global__ __launch_bounds__(256) void k3b_softmax(float* __restrict__ ws)
{
  const int i = blockIdx.x, t = threadIdx.x;
  const int lane = t & 63, w4 = t >> 6;
  u32* WB = (u32*)(ws + OFF_WB);
  const int ks = lane >> 2, d = lane & 3;
#pragma unroll
  for (int hh = 0; hh < 2; ++hh) {
    const int h = w4 + hh*4;
    u32 dv[4]; float v[8];
#pragma unroll
    for (int lg = 0; lg < 4; ++lg) {
      dv[lg] = WB[(i*16 + ks)*128 + (lg*8 + h)*4 + d];
      v[lg*2]   = f16lo(dv[lg]);
      v[lg*2+1] = f16hi(dv[lg]);
    }
    float m = v[0];
#pragma unroll
    for (int r = 1; r < 8; ++r) m = fmaxf(m, v[r]);
    m = wredMax(m);
    float s = 0.f;
#pragma unroll
    for (int r = 0; r < 8; ++r) { v[r] = __expf(v[r] - m); s += v[r]; }
    s = wredSum(s);
    const float rz = __builtin_amdgcn_rcpf(s);
#pragma unroll
    for (int lg = 0; lg < 4; ++lg)
      WB[(i*16 + ks)*128 + (lg*8 + h)*4 + d] = cvtpk(v[lg*2]*rz, v[lg*2+1]*rz);
  }
}

// ---------- K3c: G-GEMM + ctx1 + ctx2 + residual + LN2 (Mi=2, 256 blocks) ----------
__global__ __launch_bounds__(512, 2) void k3c_ctx(
    const float* __restrict__ x, const float* __restrict__ coords,
    const float* __restrict__ rv1_w, const float* __restrict__ rv1_b,
    const float* __restrict__ rv2_b, const float* __restrict__ ln2_w,
    const float* __restrict__ ln2_b, float* __restrict__ ws)
{
  __shared__ __align__(16) float aV2[2][DD];
  __shared__ __align__(16) float eV2[2][DD];
  __shared__ __align__(16) float Gs[2][HH][260];
  __shared__ __align__(16) float x2t[2][257];
  __shared__ float red[2][4];
  const int bx = blockIdx.x, t = threadIdx.x, i0 = bx*2;
  const int lane = t & 63, w = t >> 6, lm = lane & 15, lg = lane >> 4;
  {
    const int ii = t >> 8, e = t & 255;
    const float pv = coords[(i0+ii)*3]*rv1_w[e*3] + coords[(i0+ii)*3+1]*rv1_w[e*3+1]
                   + coords[(i0+ii)*3+2]*rv1_w[e*3+2] + rv1_b[e];
    aV2[ii][e] = pv; eV2[ii][e] = __expf(-pv);
  }
  __syncthreads();
  const uint4* WBu = (const uint4*)(ws + OFF_WB);
  const uint4* PVu = (const uint4*)(ws + OFF_PV);
  const uint4* VTu = (const uint4*)(ws + OFF_VT);
  const uint4* RVu = (const uint4*)(ws + OFF_RV2F);
  f32x4 z = {0,0,0,0};
  f32x4 accg[2][2] = {{z,z},{z,z}};
  f32x4 ac1[2] = {z,z};
  float aV[2][2], eV[2][2];
#pragma unroll
  for (int e2 = 0; e2 < 2; ++e2)
#pragma unroll
    for (int ig = 0; ig < 2; ++ig) {
      aV[e2][ig] = aV2[ig][(w*2+e2)*16 + lm];
      eV[e2][ig] = eV2[ig][(w*2+e2)*16 + lm];
    }
  for (int ks = 0; ks < 16; ++ks) {
    bf16x8 wfr[2];
#pragma unroll
    for (int ig = 0; ig < 2; ++ig) {
      const uint4 wd = WBu[((i0+ig)*16 + ks)*32 + lg*8 + lm];   // lm>=8 garbage ok
      wfr[ig] = mkfrag(wd.x,wd.y,wd.z,wd.w);
    }
    const uint4 cd = WBu[((i0+lm)*16 + ks)*32 + lg*8 + w];      // lm>=2 garbage ok
    const bf16x8 c1b = mkfrag(cd.x,cd.y,cd.z,cd.w);
#pragma unroll
    for (int e2 = 0; e2 < 2; ++e2) {
      const int et = w*2 + e2;
      const uint4 pd = PVu[(et*16 + ks)*64 + lane];
      float p[8], ep[8];
      p[0]=f16lo(pd.x); p[1]=f16hi(pd.x); p[2]=f16lo(pd.y); p[3]=f16hi(pd.y);
      p[4]=f16lo(pd.z); p[5]=f16hi(pd.z); p[6]=f16lo(pd.w); p[7]=f16hi(pd.w);
#pragma unroll
      for (int r = 0; r < 8; ++r) ep[r] = __expf(p[r]);
#pragma unroll
      for (int ig = 0; ig < 2; ++ig) {
        float s[8];
#pragma unroll
        for (int r = 0; r < 8; ++r)
          s[r] = (aV[e2][ig] - p[r]) * __builtin_amdgcn_rcpf(fmaf(eV[e2][ig], ep[r], 1.f));
        const bf16x8 afr = mkfrag(cvtpk(s[0],s[1]), cvtpk(s[2],s[3]),
                                  cvtpk(s[4],s[5]), cvtpk(s[6],s[7]));
        accg[e2][ig] = __builtin_amdgcn_mfma_f32_16x16x32_bf16(afr, wfr[ig], accg[e2][ig], 0,0,0);
      }
    }
#pragma unroll
    for (int m2 = 0; m2 < 2; ++m2) {
      const int c = (w*2 + m2)*16 + lm;
      const uint4 vd = VTu[c*64 + ks*4 + lg];
      const bf16x8 vfr = mkfrag(vd.x,vd.y,vd.z,vd.w);
      ac1[m2] = __builtin_amdgcn_mfma_f32_16x16x32_bf16(vfr, c1b, ac1[m2], 0,0,0);
    }
  }
  if (lm < HH) {
#pragma unroll
    for (int e2 = 0; e2 < 2; ++e2)
#pragma unroll
      for (int ig = 0; ig < 2; ++ig)
#pragma unroll
        for (int g = 0; g < 4; ++g)
          Gs[ig][lm][(w*2+e2)*16 + lg*4 + g] = accg[e2][ig][g];
  }
  __syncthreads();
  f32x4 ac2[2] = {z,z};
  const int il = lm & 1;
  for (int k2 = 0; k2 < 8; ++k2) {
    const float4 g0 = *(const float4*)&Gs[il][w][k2*32 + lg*8];
    const float4 g1 = *(const float4*)&Gs[il][w][k2*32 + lg*8 + 4];
    const bf16x8 gfr = mkfrag(cvtpk(g0.x,g0.y), cvtpk(g0.z,g0.w),
                              cvtpk(g1.x,g1.y), cvtpk(g1.z,g1.w));
#pragma unroll
    for (int m2 = 0; m2 < 2; ++m2) {
      const uint4 ad = RVu[((w*2+m2)*8 + k2)*64 + lane];
      const bf16x8 afr = mkfrag(ad.x,ad.y,ad.z,ad.w);
      ac2[m2] = __builtin_amdgcn_mfma_f32_16x16x32_bf16(afr, gfr, ac2[m2], 0,0,0);
    }
  }
#pragma unroll
  for (int m2 = 0; m2 < 2; ++m2) {
    const int c0 = (w*2 + m2)*16 + lg*4;
    const float4 rb = *(const float4*)(rv2_b + c0);
    if (lm < 2) {
      const float4 xv = *(const float4*)(x + (i0+lm)*DD + c0);
      x2t[lm][c0+0] = ac1[m2][0] + ac2[m2][0] + rb.x + xv.x;
      x2t[lm][c0+1] = ac1[m2][1] + ac2[m2][1] + rb.y + xv.y;
      x2t[lm][c0+2] = ac1[m2][2] + ac2[m2][2] + rb.z + xv.z;
      x2t[lm][c0+3] = ac1[m2][3] + ac2[m2][3] + rb.w + xv.w;
    }
  }
  __syncthreads();
  const int ii = t >> 8, c = t & 255;
  const float v = x2t[ii][c];
  float s1 = wredSum(v);
  if (lane == 0) red[ii][w & 3] = s1;
  __syncthreads();
  const float mu = (red[ii][0]+red[ii][1]+red[ii][2]+red[ii][3]) * (1.0f/DD);
  const float dv = v - mu;
  float s2 = wredSum(dv*dv);
  __syncthreads();
  if (lane == 0) red[ii][w & 3] = s2;
  __syncthreads();
  const float var = (red[ii][0]+red[ii][1]+red[ii][2]+red[ii][3]) * (1.0f/DD);
  const float rstd = rsqrtf(var + 1e-5f);
  ws[OFF_X2  + (i0+ii)*DD + c] = v;
  ws[OFF_XN2 + (i0+ii)*DD + c] = dv*rstd*ln2_w[c] + ln2_b[c];
}

// ---------- K3p: pack FFN weights into dead regions ----------
__global__ __launch_bounds__(256) void k3p_pack(
    const float* __restrict__ w1, const float* __restrict__ w2,
    const float* __restrict__ w3, float* __restrict__ ws)
{
  const int b = blockIdx.x, t = threadIdx.x;
  if (b < 88) {                         // W12P f4[k4][682][2]
    float4* dst = (float4*)(ws + OFF_W12P);
    for (int L4 = b*256 + t; L4 < 87296; L4 += 88*256) {
      const int pr = L4 & 1, rest = L4 >> 1;
      const int O = rest % 682, k4 = rest / 682;
      dst[L4] = *(const float4*)((pr ? w2 : w1) + O*DD + k4*4);
    }
  } else {                              // W3P f2[341][256]
    float2* dst = (float2*)(ws + OFF_W3P);
    for (int L2 = (b-88)*256 + t; L2 < 87296; L2 += 44*256) {
      const int c = L2 & 255, k2i = L2 >> 8;
      dst[L2] = *(const float2*)(w3 + c*HIDN + 2*k2i);
    }
  }
}

// ---------- K4: SwiGLU up-projections, Mi=16 ----------
__global__ __launch_bounds__(256) void k4_ffn1(
    float* __restrict__ ws, const float* __restrict__ b1, const float* __restrict__ b2)
{
  const int i0 = blockIdx.x*16, rep = blockIdx.y, t = threadIdx.x;
  const int O = rep*DD + t;
  if (O >= HIDN) return;
  const float4* xn4 = (const float4*)(ws + OFF_XN2);
  const float4* wp4 = (const float4*)(ws + OFF_W12P);
  float a1[16], a2[16];
  const float bb1 = b1[O], bb2 = b2[O];
#pragma unroll
  for (int r = 0; r < 16; ++r) { a1[r] = bb1; a2[r] = bb2; }
  for (int k4 = 0; k4 < 64; ++k4) {
    const float4 u = wp4[(k4*HIDN + O)*2];
    const float4 v = wp4[(k4*HIDN + O)*2 + 1];
#pragma unroll
    for (int r = 0; r < 16; ++r) {
      const float4 xv = xn4[(i0+r)*64 + k4];  // uniform -> s_load
      a1[r] += dot4(xv, u); a2[r] += dot4(xv, v);
    }
  }
#pragma unroll
  for (int r = 0; r < 16; ++r)
    ws[OFF_H1 + (size_t)(i0+r)*HIDN + O] = fsilu(a1[r]) * a2[r];
}

// ---------- K5: down-projection + residual, Mi=16, c-halves ----------
__global__ __launch_bounds__(128) void k5_ffn2(
    const float* __restrict__ ws, const float* __restrict__ b3, float* __restrict__ out)
{
  const int i0 = blockIdx.x*16, ch = blockIdx.y, t = threadIdx.x;
  const int c = ch*128 + t;
  const float2* wp2 = (const float2*)(ws + OFF_W3P);
  float acc[16];
  const float bb = b3[c];
#pragma unroll
  for (int r = 0; r < 16; ++r) acc[r] = bb + ws[OFF_X2 + (i0+r)*DD + c];
  for (int k = 0; k < 341; ++k) {
    const float2 wv = wp2[k*DD + c];
#pragma unroll
    for (int r = 0; r < 16; ++r) {
      const float2 hv = *(const float2*)(ws + OFF_H1 + (size_t)(i0+r)*HIDN + 2*k);
      acc[r] += hv.x*wv.x + hv.y*wv.y;        // h rows uniform -> s_load
    }
  }
#pragma unroll
  for (int r = 0; r < 16; ++r) out[(i0+r)*DD + c] = acc[r];
}

extern "C" void kernel_launch(void* const* d_in, const int* in_sizes, int n_in,
                              void* d_out, int out_size, void* d_ws, size_t ws_size,
                              hipStream_t stream) {
  (void)in_sizes; (void)n_in; (void)out_size; (void)ws_size;
  const float* x      = (const float*)d_in[0];
  const float* coords = (const float*)d_in[1];
  const float* ln1_w  = (const float*)d_in[2];
  const float* ln1_b  = (const float*)d_in[3];
  const float* ln2_w  = (const float*)d_in[4];
  const float* ln2_b  = (const float*)d_in[5];
  const float* qkv_w  = (const float*)d_in[6];
  const float* qkv_b  = (const float*)d_in[7];
  const float* rb1_w  = (const float*)d_in[8];
  const float* rb1_b  = (const float*)d_in[9];
  const float* rb2_w  = (const float*)d_in[10];
  /* d_in[11] = rb2_b cancels in softmax */
  const float* rv1_w  = (const float*)d_in[12];
  const float* rv1_b  = (const float*)d_in[13];
  const float* rv2_w  = (const float*)d_in[14];
  const float* rv2_b  = (const float*)d_in[15];
  const float* ffn_w1 = (const float*)d_in[16];
  const float* ffn_b1 = (const float*)d_in[17];
  const float* ffn_w2 = (const float*)d_in[18];
  const float* ffn_b2 = (const float*)d_in[19];
  const float* ffn_w3 = (const float*)d_in[20];
  const float* ffn_b3 = (const float*)d_in[21];
  float* ws  = (float*)d_ws;
  float* out = (float*)d_out;

  k1_prep<<<601, 256, 0, stream>>>(x, coords, ln1_w, ln1_b, rb1_w, rv1_w,
                                   rv2_w, rb2_w, qkv_w, ws);
  k2_qkv<<<dim3(256, 3), 256, 0, stream>>>(ws, qkv_b);
  k3a_scores<<<512, 256, 0, stream>>>(coords, rb1_w, rb1_b, ws);
  k3b_softmax<<<512, 256, 0, stream>>>(ws);
  k3c_ctx<<<256, 512, 0, stream>>>(x, coords, rv1_w, rv1_b, rv2_b, ln2_w, ln2_b, ws);
  k3p_pack<<<132, 256, 0, stream>>>(ffn_w1, ffn_w2, ffn_w3, ws);
  k4_ffn1<<<dim3(32, 3), 256, 0, stream>>>(ws, ffn_b1, ffn_b2);
  k5_ffn2<<<dim3(32, 2), 128, 0, stream>>>(ws, ffn_b3, out);
}

// Round 7
// 208.969 us; speedup vs baseline: 1.6117x; 1.6117x over previous
//
#include <hip/hip_runtime.h>

// Point transformer B=1 N=512 D=256 H=8 HD=32 CD=3 HID=682.
// hidden[i,j,e] = silu(aI[e]-p[j,e]); e^{-(aI-p)} = e^{-aI} * e^{p}.
// rel_value contracted: G[i,h,e]=sum_j w*silu_v -> ctx2 = G@rv2^T + rv2_b (exact).
// rb2_b cancels in softmax.
// WB buffer holds scores/weights in MFMA B-fragment order (f16 raw scores ->
// in-place softmax -> bf16 weights), consumed by G-GEMM and ctx1-GEMM.
// FFN kernels: LDS-staged activation rows (broadcast reads) + coalesced
// k-major weights; high-occupancy grids (fix for round-6's 1.4%-occupancy k5).

#define NN 512
#define DD 256
#define HH 8
#define HIDN 682
#define QKSCALE 0.17677669529663687f

// ---- workspace (floats); max end = 1,507,392 = 5.90 MB ----
#define OFF_QB    0        // [65536]  q*scale bf16 rows [i][128dw]   (k2->k3a)
#define OFF_PB    65536    // [65536]  p_b f16 frags [jt][ks][lane]u4 (k1->k3a)
#define OFF_X2    0        // [131072] x+attn (k3c->k5)  overlays QB/PB
#define OFF_KF    131072   // [65536]  k bf16 A-frags (k2->k3a)
#define OFF_RB2F  196608   // [2048]   rb2 B-frags (k1->k3a)
#define OFF_XN2   131072   // [131072] LN2 out (k3c->k4) overlays KF/RB2F
#define OFF_RV2F  262144   // [32768]  rv2 bf16 A-frags [mt][ks2][lane]u4 (k1->k3c)
#define OFF_VT    294912   // [65536]  v^T bf16 [c][256dw] (k2->k3c)
#define OFF_PV    360448   // [65536]  p_v f16 frags [et][ks][lane]u4 (k1->k3c)
#define OFF_WB    425984   // [1081408] scores/weights [528i][16ks][32slot][4dw]+64
#define OFF_XN    425984   // [131072] LN1 out (k1->k2, inside WB region)
#define OFF_QKVP  557056   // [196608] qkv_w k-major f4 (k1->k2, inside WB region)
#define OFF_W12P  425984   // [349184] ffn w1/w2 k-major (k3p->k4, WB dead)
#define OFF_W3P   775168   // [174592] ffn w3 k-major (k3p->k5)
#define OFF_H1    949760   // [349184] swiglu hidden (k4->k5)

typedef float  f32x4  __attribute__((ext_vector_type(4)));
typedef short  bf16x8 __attribute__((ext_vector_type(8)));
typedef __fp16 fp16x2 __attribute__((ext_vector_type(2)));
typedef unsigned int u32;

static __device__ __forceinline__ float wredSum(float v){
#pragma unroll
  for (int o = 1; o < 64; o <<= 1) v += __shfl_xor(v, o, 64);
  return v;
}
static __device__ __forceinline__ float wredMax(float v){
#pragma unroll
  for (int o = 1; o < 64; o <<= 1) v = fmaxf(v, __shfl_xor(v, o, 64));
  return v;
}
static __device__ __forceinline__ float fsilu(float x){
  return x * __builtin_amdgcn_rcpf(1.0f + __expf(-x));
}
static __device__ __forceinline__ u32 cvtpk(float lo, float hi){  // 2xf32 -> bf16 pair
  u32 d; asm("v_cvt_pk_bf16_f32 %0, %1, %2" : "=v"(d) : "v"(lo), "v"(hi));
  return d;
}
static __device__ __forceinline__ u32 pkf16(float lo, float hi){  // 2xf32 -> f16 pair
  fp16x2 r = __builtin_amdgcn_cvt_pkrtz(lo, hi);
  union{fp16x2 h; u32 u;} c; c.h = r; return c.u;
}
static __device__ __forceinline__ float f16lo(u32 d){
  union{unsigned short s; __fp16 h;} c; c.s = (unsigned short)(d & 0xffffu); return (float)c.h;
}
static __device__ __forceinline__ float f16hi(u32 d){
  union{unsigned short s; __fp16 h;} c; c.s = (unsigned short)(d >> 16); return (float)c.h;
}
static __device__ __forceinline__ bf16x8 mkfrag(u32 a, u32 b, u32 c, u32 d){
  union{u32 u[4]; bf16x8 s;} f; f.u[0]=a; f.u[1]=b; f.u[2]=c; f.u[3]=d; return f.s;
}
static __device__ __forceinline__ float dot4(float4 a, float4 b){
  return a.x*b.x + a.y*b.y + a.z*b.z + a.w*b.w;
}

// ---------- K1: LN1 + table builders (601 blocks) ----------
__global__ __launch_bounds__(256) void k1_prep(
    const float* __restrict__ x, const float* __restrict__ coords,
    const float* __restrict__ ln1_w, const float* __restrict__ ln1_b,
    const float* __restrict__ rb1_w, const float* __restrict__ rv1_w,
    const float* __restrict__ rv2_w, const float* __restrict__ rb2_w,
    const float* __restrict__ qkv_w, float* __restrict__ ws)
{
  __shared__ float r4[4];
  const int b = blockIdx.x, t = threadIdx.x;
  if (b < 512) {                         // ---- LN1 ----
    const int lane = t & 63, wid = t >> 6;
    const float v = x[b*DD + t];
    float s = wredSum(v);
    if (lane == 0) r4[wid] = s;
    __syncthreads();
    const float mu = (r4[0]+r4[1]+r4[2]+r4[3]) * (1.0f/DD);
    const float d = v - mu;
    float s2 = wredSum(d*d);
    __syncthreads();
    if (lane == 0) r4[wid] = s2;
    __syncthreads();
    const float var = (r4[0]+r4[1]+r4[2]+r4[3]) * (1.0f/DD);
    ws[OFF_XN + b*DD + t] = d*rsqrtf(var + 1e-5f)*ln1_w[t] + ln1_b[t];
  } else if (b < 528) {                  // ---- PB f16 frags ----
    u32* PB32 = (u32*)(ws + OFF_PB);
#pragma unroll
    for (int k = 0; k < 4; ++k) {
      const int L = (b-512)*1024 + k*256 + t;           // uint4 index
      const int jt = L >> 9, ks = (L >> 6) & 7, ln = L & 63;
      const int lmm = ln & 15, lgg = ln >> 4;
      const int j = jt*16 + lmm, e0 = ks*32 + lgg*8;
      const float c0 = coords[j*3], c1 = coords[j*3+1], c2 = coords[j*3+2];
      float p[8];
#pragma unroll
      for (int r = 0; r < 8; ++r)
        p[r] = c0*rb1_w[(e0+r)*3] + c1*rb1_w[(e0+r)*3+1] + c2*rb1_w[(e0+r)*3+2];
      uint4 q; q.x = pkf16(p[0],p[1]); q.y = pkf16(p[2],p[3]);
      q.z = pkf16(p[4],p[5]); q.w = pkf16(p[6],p[7]);
      *(uint4*)(PB32 + (size_t)L*4) = q;
    }
  } else if (b < 544) {                  // ---- PV f16 frags ----
    u32* PV32 = (u32*)(ws + OFF_PV);
#pragma unroll
    for (int k = 0; k < 4; ++k) {
      const int L = (b-528)*1024 + k*256 + t;
      const int et = L >> 10, ks = (L >> 6) & 15, ln = L & 63;
      const int lmm = ln & 15, lgg = ln >> 4;
      const int e = et*16 + lmm, j0 = ks*32 + lgg*8;
      const float w0 = rv1_w[e*3], w1 = rv1_w[e*3+1], w2 = rv1_w[e*3+2];
      float p[8];
#pragma unroll
      for (int r = 0; r < 8; ++r)
        p[r] = coords[(j0+r)*3]*w0 + coords[(j0+r)*3+1]*w1 + coords[(j0+r)*3+2]*w2;
      uint4 q; q.x = pkf16(p[0],p[1]); q.y = pkf16(p[2],p[3]);
      q.z = pkf16(p[4],p[5]); q.w = pkf16(p[6],p[7]);
      *(uint4*)(PV32 + (size_t)L*4) = q;
    }
  } else if (b < 552) {                  // ---- RV2F bf16 A-frags ----
    u32* RV32 = (u32*)(ws + OFF_RV2F);
#pragma unroll
    for (int k = 0; k < 4; ++k) {
      const int L = (b-544)*1024 + k*256 + t;
      const int mt = L >> 9, ks2 = (L >> 6) & 7, ln = L & 63;
      const int lmm = ln & 15, lgg = ln >> 4;
      const int c = mt*16 + lmm, e0 = ks2*32 + lgg*8;
      const float4 f0 = *(const float4*)(rv2_w + c*DD + e0);
      const float4 f1 = *(const float4*)(rv2_w + c*DD + e0 + 4);
      uint4 q; q.x = cvtpk(f0.x,f0.y); q.y = cvtpk(f0.z,f0.w);
      q.z = cvtpk(f1.x,f1.y); q.w = cvtpk(f1.z,f1.w);
      *(uint4*)(RV32 + (size_t)L*4) = q;
    }
  } else if (b == 552) {                 // ---- RB2F B-frags ----
    u32* RBF = (u32*)(ws + OFF_RB2F);
    const int l = t & 63, lmm = l & 15, lgg = (l >> 4) & 3, kq = t >> 6;
#pragma unroll
    for (int g = 0; g < 2; ++g) {
      const int ks = g*4 + kq;
      u32 dw[4];
#pragma unroll
      for (int dd = 0; dd < 4; ++dd) {
        const int e0 = ks*32 + lgg*8 + 2*dd;
        const float f0 = (lmm < HH) ? rb2_w[lmm*DD + e0]     : 0.f;
        const float f1 = (lmm < HH) ? rb2_w[lmm*DD + e0 + 1] : 0.f;
        dw[dd] = cvtpk(f0, f1);
      }
      uint4 q4; q4.x = dw[0]; q4.y = dw[1]; q4.z = dw[2]; q4.w = dw[3];
      *(uint4*)(RBF + (ks*64 + l)*4) = q4;
    }
  } else {                               // ---- QKVP f4[k4][768] ----
    float4* dst = (float4*)(ws + OFF_QKVP);
#pragma unroll
    for (int k = 0; k < 4; ++k) {
      const int L4 = (b - 553)*1024 + k*256 + t;
      const int O = L4 % 768, k4 = L4 / 768;
      dst[L4] = *(const float4*)(qkv_w + O*DD + k4*4);
    }
  }
}

// ---------- K2: QKV GEMM -> QB (q*scale bf16), KF (k frags), VT (v^T bf16) ----------
__global__ __launch_bounds__(256) void k2_qkv(
    float* __restrict__ ws, const float* __restrict__ qkv_b)
{
  const int i0 = blockIdx.x*2, rep = blockIdx.y, t = threadIdx.x;
  const int O = rep*DD + t;
  const float4* xn4 = (const float4*)(ws + OFF_XN);
  const float4* wp4 = (const float4*)(ws + OFF_QKVP);
  float a0 = qkv_b[O], a1 = a0;
  for (int k4 = 0; k4 < 64; ++k4) {
    const float4 w = wp4[k4*768 + O];
    const float4 x0 = xn4[i0*64 + k4];        // uniform -> s_load
    const float4 x1 = xn4[i0*64 + 64 + k4];
    a0 += dot4(x0, w);
    a1 += dot4(x1, w);
  }
  if (rep == 0) {                             // q*scale -> bf16 rows [i][128dw]
    u32* QB = (u32*)(ws + OFF_QB);
    const float s0 = a0*QKSCALE, s1 = a1*QKSCALE;
    const float p0 = __shfl_xor(s0, 1);
    const float p1 = __shfl_xor(s1, 1);
    if ((t & 1) == 0) {
      QB[i0*128 + (t >> 1)]     = cvtpk(s0, p0);
      QB[(i0+1)*128 + (t >> 1)] = cvtpk(s1, p1);
    }
  } else if (rep == 1) {                      // k -> bf16 A-fragment layout
    u32* KF = (u32*)(ws + OFF_KF);
    const float p0 = __shfl_xor(a0, 1);
    const float p1 = __shfl_xor(a1, 1);
    if ((t & 1) == 0) {
      const int hq = t >> 5, lgk = (t >> 3) & 3, dw = (t & 7) >> 1;
      const int jt0_ = i0 >> 4, lm0 = i0 & 15;
      KF[(((jt0_*8 + hq)*4 + lgk)*16 + lm0)*4 + dw] = cvtpk(a0, p0);
      const int j1 = i0 + 1, jt1_ = j1 >> 4, lm1 = j1 & 15;
      KF[(((jt1_*8 + hq)*4 + lgk)*16 + lm1)*4 + dw] = cvtpk(a1, p1);
    }
  } else {                                    // v^T bf16 [c][256dw], dword = j-pair
    u32* VT = (u32*)(ws + OFF_VT);
    VT[t*256 + (i0 >> 1)] = cvtpk(a0, a1);
  }
}

// ---------- K3a: scores (bias-GEMM + qk) -> WB raw f16, Mi=4 x j-quarter ----------
__global__ __launch_bounds__(256, 2) void k3a_scores(
    const float* __restrict__ coords, const float* __restrict__ rb1_w,
    const float* __restrict__ rb1_b, float* __restrict__ ws)
{
  __shared__ __align__(16) float aI4[4][DD];
  __shared__ __align__(16) float eI4[4][DD];
  const int bx = blockIdx.x, t = threadIdx.x;
  const int it = bx >> 2, jq = bx & 3, i0 = it*4;
  const int lane = t & 63, w = t >> 6, lm = lane & 15, lg = lane >> 4;
  {
    const float w0 = rb1_w[t*3], w1 = rb1_w[t*3+1], w2 = rb1_w[t*3+2], bb = rb1_b[t];
#pragma unroll
    for (int i = 0; i < 4; ++i) {
      const float a = coords[(i0+i)*3]*w0 + coords[(i0+i)*3+1]*w1
                    + coords[(i0+i)*3+2]*w2 + bb;
      aI4[i][t] = a; eI4[i][t] = __expf(-a);
    }
  }
  __syncthreads();
  const uint4* PBu = (const uint4*)(ws + OFF_PB);
  const uint4* KFu = (const uint4*)(ws + OFF_KF);
  const uint4* QBu = (const uint4*)(ws + OFF_QB);
  const u32*   RBF = (const u32*)(ws + OFF_RB2F);
  const int jtA = jq*8 + w*2;
  f32x4 z = {0,0,0,0};
  f32x4 acc[2][4] = {{z,z,z,z},{z,z,z,z}};
  for (int ks = 0; ks < 8; ++ks) {
    const uint4 bd = *(const uint4*)(RBF + (ks*64 + lane)*4);
    const bf16x8 bfr = mkfrag(bd.x,bd.y,bd.z,bd.w);
    float4 aA[4][2], eA[4][2];
#pragma unroll
    for (int i = 0; i < 4; ++i) {
      aA[i][0] = *(const float4*)&aI4[i][ks*32 + lg*8];
      aA[i][1] = *(const float4*)&aI4[i][ks*32 + lg*8 + 4];
      eA[i][0] = *(const float4*)&eI4[i][ks*32 + lg*8];
      eA[i][1] = *(const float4*)&eI4[i][ks*32 + lg*8 + 4];
    }
#pragma unroll
    for (int j2 = 0; j2 < 2; ++j2) {
      const uint4 pd = PBu[((jtA+j2)*8 + ks)*64 + lane];
      float p[8], ep[8];
      p[0]=f16lo(pd.x); p[1]=f16hi(pd.x); p[2]=f16lo(pd.y); p[3]=f16hi(pd.y);
      p[4]=f16lo(pd.z); p[5]=f16hi(pd.z); p[6]=f16lo(pd.w); p[7]=f16hi(pd.w);
#pragma unroll
      for (int r = 0; r < 8; ++r) ep[r] = __expf(p[r]);
#pragma unroll
      for (int i = 0; i < 4; ++i) {
        const float* aa = (const float*)&aA[i][0];
        const float* ee = (const float*)&eA[i][0];
        float s[8];
#pragma unroll
        for (int r = 0; r < 8; ++r)
          s[r] = (aa[r] - p[r]) * __builtin_amdgcn_rcpf(fmaf(ee[r], ep[r], 1.f));
        const bf16x8 afr = mkfrag(cvtpk(s[0],s[1]), cvtpk(s[2],s[3]),
                                  cvtpk(s[4],s[5]), cvtpk(s[6],s[7]));
        acc[j2][i] = __builtin_amdgcn_mfma_f32_16x16x32_bf16(afr, bfr, acc[j2][i], 0,0,0);
      }
    }
  }
#pragma unroll
  for (int hq = 0; hq < 8; ++hq) {
    uint4 qd[4];
#pragma unroll
    for (int i = 0; i < 4; ++i) qd[i] = QBu[(i0+i)*32 + hq*4 + lg];
    const bool sel = (lm == hq);
#pragma unroll
    for (int j2 = 0; j2 < 2; ++j2) {
      const uint4 kd = KFu[((jtA+j2)*8 + hq)*64 + lane];
      const bf16x8 kfr = mkfrag(kd.x,kd.y,kd.z,kd.w);
#pragma unroll
      for (int i = 0; i < 4; ++i) {
        const bf16x8 qfr = mkfrag(sel?qd[i].x:0u, sel?qd[i].y:0u,
                                  sel?qd[i].z:0u, sel?qd[i].w:0u);
        acc[j2][i] = __builtin_amdgcn_mfma_f32_16x16x32_bf16(kfr, qfr, acc[j2][i], 0,0,0);
      }
    }
  }
  // store raw f16 scores into WB fragment layout
  u32* WB = (u32*)(ws + OFF_WB);
  if (lm < HH) {
#pragma unroll
    for (int j2 = 0; j2 < 2; ++j2) {
      const int jt = jtA + j2, j0 = jt*16 + lg*4;
      const int ksw = j0 >> 5, rr = j0 & 31, lgw = rr >> 3, d0 = (rr & 7) >> 1;
#pragma unroll
      for (int i = 0; i < 4; ++i) {
        const int idx = (((i0+i)*16 + ksw)*32 + lgw*8 + lm)*4 + d0;
        uint2 st; st.x = pkf16(acc[j2][i][0], acc[j2][i][1]);
        st.y = pkf16(acc[j2][i][2], acc[j2][i][3]);
        *(uint2*)(WB + idx) = st;
      }
    }
  }
}

// ---------- K3b: softmax in-place on WB (f16 scores -> bf16 weights) ----------
__global__ __launch_bounds__(256) void k3b_softmax(float* __restrict__ ws)
{
  const int i = blockIdx.x, t = threadIdx.x;
  const int lane = t & 63, w4 = t >> 6;
  u32* WB = (u32*)(ws + OFF_WB);
  const int ks = lane >> 2, d = lane & 3;
#pragma unroll
  for (int hh = 0; hh < 2; ++hh) {
    const int h = w4 + hh*4;
    u32 dv[4]; float v[8];
#pragma unroll
    for (int lg = 0; lg < 4; ++lg) {
      dv[lg] = WB[(i*16 + ks)*128 + (lg*8 + h)*4 + d];
      v[lg*2]   = f16lo(dv[lg]);
      v[lg*2+1] = f16hi(dv[lg]);
    }
    float m = v[0];
#pragma unroll
    for (int r = 1; r < 8; ++r) m = fmaxf(m, v[r]);
    m = wredMax(m);
    float s = 0.f;
#pragma unroll
    for (int r = 0; r < 8; ++r) { v[r] = __expf(v[r] - m); s += v[r]; }
    s = wredSum(s);
    const float rz = __builtin_amdgcn_rcpf(s);
#pragma unroll
    for (int lg = 0; lg < 4; ++lg)
      WB[(i*16 + ks)*128 + (lg*8 + h)*4 + d] = cvtpk(v[lg*2]*rz, v[lg*2+1]*rz);
  }
}

// ---------- K3c: G-GEMM + ctx1 + ctx2 + residual + LN2 (Mi=2, 256 blocks) ----------
__global__ __launch_bounds__(512, 2) void k3c_ctx(
    const float* __restrict__ x, const float* __restrict__ coords,
    const float* __restrict__ rv1_w, const float* __restrict__ rv1_b,
    const float* __restrict__ rv2_b, const float* __restrict__ ln2_w,
    const float* __restrict__ ln2_b, float* __restrict__ ws)
{
  __shared__ __align__(16) float aV2[2][DD];
  __shared__ __align__(16) float eV2[2][DD];
  __shared__ __align__(16) float Gs[2][HH][260];
  __shared__ __align__(16) float x2t[2][257];
  __shared__ float red[2][4];
  const int bx = blockIdx.x, t = threadIdx.x, i0 = bx*2;
  const int lane = t & 63, w = t >> 6, lm = lane & 15, lg = lane >> 4;
  {
    const int ii = t >> 8, e = t & 255;
    const float pv = coords[(i0+ii)*3]*rv1_w[e*3] + coords[(i0+ii)*3+1]*rv1_w[e*3+1]
                   + coords[(i0+ii)*3+2]*rv1_w[e*3+2] + rv1_b[e];
    aV2[ii][e] = pv; eV2[ii][e] = __expf(-pv);
  }
  __syncthreads();
  const uint4* WBu = (const uint4*)(ws + OFF_WB);
  const uint4* PVu = (const uint4*)(ws + OFF_PV);
  const uint4* VTu = (const uint4*)(ws + OFF_VT);
  const uint4* RVu = (const uint4*)(ws + OFF_RV2F);
  f32x4 z = {0,0,0,0};
  f32x4 accg[2][2] = {{z,z},{z,z}};
  f32x4 ac1[2] = {z,z};
  float aV[2][2], eV[2][2];
#pragma unroll
  for (int e2 = 0; e2 < 2; ++e2)
#pragma unroll
    for (int ig = 0; ig < 2; ++ig) {
      aV[e2][ig] = aV2[ig][(w*2+e2)*16 + lm];
      eV[e2][ig] = eV2[ig][(w*2+e2)*16 + lm];
    }
  for (int ks = 0; ks < 16; ++ks) {
    bf16x8 wfr[2];
#pragma unroll
    for (int ig = 0; ig < 2; ++ig) {
      const uint4 wd = WBu[((i0+ig)*16 + ks)*32 + lg*8 + lm];   // lm>=8 garbage ok
      wfr[ig] = mkfrag(wd.x,wd.y,wd.z,wd.w);
    }
    const uint4 cd = WBu[((i0+lm)*16 + ks)*32 + lg*8 + w];      // lm>=2 garbage ok
    const bf16x8 c1b = mkfrag(cd.x,cd.y,cd.z,cd.w);
#pragma unroll
    for (int e2 = 0; e2 < 2; ++e2) {
      const int et = w*2 + e2;
      const uint4 pd = PVu[(et*16 + ks)*64 + lane];
      float p[8], ep[8];
      p[0]=f16lo(pd.x); p[1]=f16hi(pd.x); p[2]=f16lo(pd.y); p[3]=f16hi(pd.y);
      p[4]=f16lo(pd.z); p[5]=f16hi(pd.z); p[6]=f16lo(pd.w); p[7]=f16hi(pd.w);
#pragma unroll
      for (int r = 0; r < 8; ++r) ep[r] = __expf(p[r]);
#pragma unroll
      for (int ig = 0; ig < 2; ++ig) {
        float s[8];
#pragma unroll
        for (int r = 0; r < 8; ++r)
          s[r] = (aV[e2][ig] - p[r]) * __builtin_amdgcn_rcpf(fmaf(eV[e2][ig], ep[r], 1.f));
        const bf16x8 afr = mkfrag(cvtpk(s[0],s[1]), cvtpk(s[2],s[3]),
                                  cvtpk(s[4],s[5]), cvtpk(s[6],s[7]));
        accg[e2][ig] = __builtin_amdgcn_mfma_f32_16x16x32_bf16(afr, wfr[ig], accg[e2][ig], 0,0,0);
      }
    }
#pragma unroll
    for (int m2 = 0; m2 < 2; ++m2) {
      const int c = (w*2 + m2)*16 + lm;
      const uint4 vd = VTu[c*64 + ks*4 + lg];
      const bf16x8 vfr = mkfrag(vd.x,vd.y,vd.z,vd.w);
      ac1[m2] = __builtin_amdgcn_mfma_f32_16x16x32_bf16(vfr, c1b, ac1[m2], 0,0,0);
    }
  }
  if (lm < HH) {
#pragma unroll
    for (int e2 = 0; e2 < 2; ++e2)
#pragma unroll
      for (int ig = 0; ig < 2; ++ig)
#pragma unroll
        for (int g = 0; g < 4; ++g)
          Gs[ig][lm][(w*2+e2)*16 + lg*4 + g] = accg[e2][ig][g];
  }
  __syncthreads();
  f32x4 ac2[2] = {z,z};
  const int il = lm & 1;
  for (int k2 = 0; k2 < 8; ++k2) {
    const float4 g0 = *(const float4*)&Gs[il][w][k2*32 + lg*8];
    const float4 g1 = *(const float4*)&Gs[il][w][k2*32 + lg*8 + 4];
    const bf16x8 gfr = mkfrag(cvtpk(g0.x,g0.y), cvtpk(g0.z,g0.w),
                              cvtpk(g1.x,g1.y), cvtpk(g1.z,g1.w));
#pragma unroll
    for (int m2 = 0; m2 < 2; ++m2) {
      const uint4 ad = RVu[((w*2+m2)*8 + k2)*64 + lane];
      const bf16x8 afr = mkfrag(ad.x,ad.y,ad.z,ad.w);
      ac2[m2] = __builtin_amdgcn_mfma_f32_16x16x32_bf16(afr, gfr, ac2[m2], 0,0,0);
    }
  }
#pragma unroll
  for (int m2 = 0; m2 < 2; ++m2) {
    const int c0 = (w*2 + m2)*16 + lg*4;
    const float4 rb = *(const float4*)(rv2_b + c0);
    if (lm < 2) {
      const float4 xv = *(const float4*)(x + (i0+lm)*DD + c0);
      x2t[lm][c0+0] = ac1[m2][0] + ac2[m2][0] + rb.x + xv.x;
      x2t[lm][c0+1] = ac1[m2][1] + ac2[m2][1] + rb.y + xv.y;
      x2t[lm][c0+2] = ac1[m2][2] + ac2[m2][2] + rb.z + xv.z;
      x2t[lm][c0+3] = ac1[m2][3] + ac2[m2][3] + rb.w + xv.w;
    }
  }
  __syncthreads();
  const int ii = t >> 8, c = t & 255;
  const float v = x2t[ii][c];
  float s1 = wredSum(v);
  if (lane == 0) red[ii][w & 3] = s1;
  __syncthreads();
  const float mu = (red[ii][0]+red[ii][1]+red[ii][2]+red[ii][3]) * (1.0f/DD);
  const float dv = v - mu;
  float s2 = wredSum(dv*dv);
  __syncthreads();
  if (lane == 0) red[ii][w & 3] = s2;
  __syncthreads();
  const float var = (red[ii][0]+red[ii][1]+red[ii][2]+red[ii][3]) * (1.0f/DD);
  const float rstd = rsqrtf(var + 1e-5f);
  ws[OFF_X2  + (i0+ii)*DD + c] = v;
  ws[OFF_XN2 + (i0+ii)*DD + c] = dv*rstd*ln2_w[c] + ln2_b[c];
}

// ---------- K3p: pack FFN weights into dead regions ----------
__global__ __launch_bounds__(256) void k3p_pack(
    const float* __restrict__ w1, const float* __restrict__ w2,
    const float* __restrict__ w3, float* __restrict__ ws)
{
  const int b = blockIdx.x, t = threadIdx.x;
  if (b < 88) {                         // W12P f4[k4][682][2]
    float4* dst = (float4*)(ws + OFF_W12P);
    for (int L4 = b*256 + t; L4 < 87296; L4 += 88*256) {
      const int pr = L4 & 1, rest = L4 >> 1;
      const int O = rest % 682, k4 = rest / 682;
      dst[L4] = *(const float4*)((pr ? w2 : w1) + O*DD + k4*4);
    }
  } else {                              // W3P f2[341][256]
    float2* dst = (float2*)(ws + OFF_W3P);
    for (int L2 = (b-88)*256 + t; L2 < 87296; L2 += 44*256) {
      const int c = L2 & 255, k2i = L2 >> 8;
      dst[L2] = *(const float2*)(w3 + c*HIDN + 2*k2i);
    }
  }
}

// ---------- K4: SwiGLU up-projections, Mi=4 + LDS-staged x rows ----------
__global__ __launch_bounds__(256) void k4_ffn1(
    float* __restrict__ ws, const float* __restrict__ b1, const float* __restrict__ b2)
{
  __shared__ __align__(16) float xr[4][DD];
  const int i0 = blockIdx.x*4, rep = blockIdx.y, t = threadIdx.x;
#pragma unroll
  for (int r = 0; r < 4; ++r) xr[r][t] = ws[OFF_XN2 + (i0+r)*DD + t];  // coalesced
  __syncthreads();
  const int O = rep*DD + t;
  if (O >= HIDN) return;   // after the only sync
  const float4* wp4 = (const float4*)(ws + OFF_W12P);
  float a1[4], a2[4];
  const float bb1 = b1[O], bb2 = b2[O];
#pragma unroll
  for (int r = 0; r < 4; ++r) { a1[r] = bb1; a2[r] = bb2; }
  for (int k4 = 0; k4 < 64; ++k4) {
    const float4 u = wp4[(k4*HIDN + O)*2];      // coalesced 64-lane
    const float4 v = wp4[(k4*HIDN + O)*2 + 1];
#pragma unroll
    for (int r = 0; r < 4; ++r) {
      const float4 xv = *(const float4*)&xr[r][k4*4];  // LDS broadcast
      a1[r] += dot4(xv, u); a2[r] += dot4(xv, v);
    }
  }
#pragma unroll
  for (int r = 0; r < 4; ++r)
    ws[OFF_H1 + (size_t)(i0+r)*HIDN + O] = fsilu(a1[r]) * a2[r];
}

// ---------- K5: down-projection + residual, Mi=2 + LDS-staged h rows ----------
__global__ __launch_bounds__(256) void k5_ffn2(
    const float* __restrict__ ws, const float* __restrict__ b3, float* __restrict__ out)
{
  __shared__ __align__(16) float hr[2][HIDN + 2];
  const int i0 = blockIdx.x*2, c = threadIdx.x;
#pragma unroll
  for (int r = 0; r < 2; ++r)
    for (int e = c; e < HIDN; e += 256)
      hr[r][e] = ws[OFF_H1 + (size_t)(i0+r)*HIDN + e];   // coalesced
  __syncthreads();
  const float2* wp2 = (const float2*)(ws + OFF_W3P);
  float acc0 = b3[c] + ws[OFF_X2 + i0*DD + c];
  float acc1 = b3[c] + ws[OFF_X2 + (i0+1)*DD + c];
  for (int k = 0; k < 341; ++k) {
    const float2 wv = wp2[k*DD + c];                     // coalesced 64-lane
    const float2 h0 = *(const float2*)&hr[0][2*k];       // LDS broadcast
    const float2 h1 = *(const float2*)&hr[1][2*k];
    acc0 += h0.x*wv.x + h0.y*wv.y;
    acc1 += h1.x*wv.x + h1.y*wv.y;
  }
  out[i0*DD + c] = acc0;
  out[(i0+1)*DD + c] = acc1;
}

extern "C" void kernel_launch(void* const* d_in, const int* in_sizes, int n_in,
                              void* d_out, int out_size, void* d_ws, size_t ws_size,
                              hipStream_t stream) {
  (void)in_sizes; (void)n_in; (void)out_size; (void)ws_size;
  const float* x      = (const float*)d_in[0];
  const float* coords = (const float*)d_in[1];
  const float* ln1_w  = (const float*)d_in[2];
  const float* ln1_b  = (const float*)d_in[3];
  const float* ln2_w  = (const float*)d_in[4];
  const float* ln2_b  = (const float*)d_in[5];
  const float* qkv_w  = (const float*)d_in[6];
  const float* qkv_b  = (const float*)d_in[7];
  const float* rb1_w  = (const float*)d_in[8];
  const float* rb1_b  = (const float*)d_in[9];
  const float* rb2_w  = (const float*)d_in[10];
  /* d_in[11] = rb2_b cancels in softmax */
  const float* rv1_w  = (const float*)d_in[12];
  const float* rv1_b  = (const float*)d_in[13];
  const float* rv2_w  = (const float*)d_in[14];
  const float* rv2_b  = (const float*)d_in[15];
  const float* ffn_w1 = (const float*)d_in[16];
  const float* ffn_b1 = (const float*)d_in[17];
  const float* ffn_w2 = (const float*)d_in[18];
  const float* ffn_b2 = (const float*)d_in[19];
  const float* ffn_w3 = (const float*)d_in[20];
  const float* ffn_b3 = (const float*)d_in[21];
  float* ws  = (float*)d_ws;
  float* out = (float*)d_out;

  k1_prep<<<601, 256, 0, stream>>>(x, coords, ln1_w, ln1_b, rb1_w, rv1_w,
                                   rv2_w, rb2_w, qkv_w, ws);
  k2_qkv<<<dim3(256, 3), 256, 0, stream>>>(ws, qkv_b);
  k3a_scores<<<512, 256, 0, stream>>>(coords, rb1_w, rb1_b, ws);
  k3b_softmax<<<512, 256, 0, stream>>>(ws);
  k3c_ctx<<<256, 512, 0, stream>>>(x, coords, rv1_w, rv1_b, rv2_b, ln2_w, ln2_b, ws);
  k3p_pack<<<132, 256, 0, stream>>>(ffn_w1, ffn_w2, ffn_w3, ws);
  k4_ffn1<<<dim3(128, 3), 256, 0, stream>>>(ws, ffn_b1, ffn_b2);
  k5_ffn2<<<256, 256, 0, stream>>>(ws, ffn_b3, out);
}